// Round 12
// baseline (580.161 us; speedup 1.0000x reference)
//
#include <hip/hip_runtime.h>

// 2-layer LSTM encoder, B=128, T=1024, F=1, HID=128, EMB=64.
// R21 = R20 (548-573us, absmax bit-exact) + two tail trims. Step = 1284cy vs
// structural floor ~1100cy = 620cy matrix pipe (32 MFMA/SIMD x 19.4cy,
// invariant under batch-packing/wave-count/tile-shape -- verified by
// arithmetic across R10-R20) + ds_read + post-wall ew + barrier.
// Trims (MFMA issue shape untouched -- R19 lesson):
//   1. ONE barrier per step, always: the chunk-boundary back-pressure poll
//      (wave0 lane0, read-only) moved ABOVE the single RAWBAR. Barrier
//      semantics still protect the ring: chunk-C stores all sit after the
//      barrier, and no wave passes it until wave0's poll clears. Deletes the
//      second RAWBAR on every 8th step.
//   2. ew chain reordered to shrink post-MFMA-wall work: compute g4[0..2],
//      c1 update and tc = tanh(c1) FIRST (their MFMAs complete ~115cy before
//      the issue wall -- 12 of 16 deps), THEN read aLo[3]/aHi[3] and do
//      sigma(g3)*tc. Post-wall chain drops ~150-200cy -> ~55-70cy.
//      Identical ops/rounding -> absmax must stay exactly 4.882812e-4.
// Protocol (R18-verified, unchanged): chunk=8 steps; prodFlag published at
// s&7==2 after s_waitcnt vmcnt(2) (chunk fully retired); back-pressure
// consFlag >= C-7 once per chunk; RAWBAR = lgkmcnt-only barrier (ring stores
// stay in flight); consumer wave 4 stages chunks into SH1 dbuf; polls bounded.

#define TB   1024
#define HID1 128
#define EMB2 64

typedef _Float16 f16x8 __attribute__((ext_vector_type(8)));
typedef float    f32x4 __attribute__((ext_vector_type(4)));

#define MFMA16(a,b,c) __builtin_amdgcn_mfma_f32_16x16x32_f16((a),(b),(c),0,0,0)

static __device__ __forceinline__ float fast_exp2(float x){
#if __has_builtin(__builtin_amdgcn_exp2f)
  return __builtin_amdgcn_exp2f(x);
#else
  return __exp2f(x);
#endif
}
static __device__ __forceinline__ float fast_rcp(float x){
#if __has_builtin(__builtin_amdgcn_rcpf)
  return __builtin_amdgcn_rcpf(x);
#else
  return 1.0f / x;
#endif
}
static __device__ __forceinline__ float sigmoid_f(float x){
  return fast_rcp(1.0f + fast_exp2(-1.44269504088896340736f * x));
}
static __device__ __forceinline__ float tanh_f(float x){
  return 1.0f - 2.0f * fast_rcp(1.0f + fast_exp2(2.88539008177792681472f * x));
}

static __device__ __forceinline__ f16x8 load_frag(const float* p){
  f16x8 r;
  #pragma unroll
  for (int j = 0; j < 8; ++j) r[j] = (_Float16)p[j];
  return r;
}

// Barrier without vmcnt drain (global stores stay in flight).
#define RAWBAR() do {                                          \
    asm volatile("s_waitcnt lgkmcnt(0)" ::: "memory");         \
    __builtin_amdgcn_s_barrier();                              \
    __builtin_amdgcn_sched_barrier(0);                         \
  } while(0)

__launch_bounds__(512, 1)
__global__ void lstm2_kernel(const float* __restrict__ x,
                             const float* __restrict__ w_ih1,
                             const float* __restrict__ w_hh1,
                             const float* __restrict__ b_ih1,
                             const float* __restrict__ b_hh1,
                             const float* __restrict__ w_ih2,
                             const float* __restrict__ w_hh2,
                             const float* __restrict__ b_ih2,
                             const float* __restrict__ b_hh2,
                             float* __restrict__ out,
                             unsigned* __restrict__ ws)
{
  __shared__ __align__(16) float    xs[TB];            // producer
  __shared__ __align__(16) _Float16 H1R[8][HID1];      // producer h1 ring
  __shared__ __align__(16) _Float16 SH1[2][8][HID1];   // consumer staged h1 (dbuf)
  __shared__ __align__(16) _Float16 H2R[8][EMB2];      // consumer h2 ring
  __shared__ unsigned readyUpTo;                       // consumer chunk gate

  const int t    = threadIdx.x;   // 0..511
  const int l    = t & 63;
  const int w    = t >> 6;        // wave 0..7
  const int col  = l & 15;
  const int quad = l >> 4;

  unsigned* prodFlag = ws;          // [128] chunks published
  unsigned* consFlag = ws + 128;    // [128] chunks consumed
  unsigned* ring     = ws + 256;    // [128][8][8][128] f32 bits

  const f32x4 zacc = {0.0f, 0.0f, 0.0f, 0.0f};

  if (blockIdx.x < 128){
    // ===================== L1 PRODUCER (batch bb) =====================
    const int bb = blockIdx.x;
    f16x8 B1[16];                    // [g][k] flattened
    float biasA[4], wxA[4];
    #pragma unroll
    for (int g = 0; g < 4; ++g){
      const int nA = (w + 8*g)*16 + col;
      biasA[g] = b_ih1[nA] + b_hh1[nA];
      wxA[g]   = w_ih1[nA];                    // w_ih1 is (512,1)
      #pragma unroll
      for (int k = 0; k < 4; ++k)
        B1[4*g + k] = load_frag(w_hh1 + nA*HID1 + k*32 + quad*8);
    }
    xs[t]       = x[bb * TB + t];
    xs[t + 512] = x[bb * TB + t + 512];
    __syncthreads();

    float c1 = 0.0f;
    const int cellA = 16*w + l;                 // valid when l<16
    const unsigned ringBase = (unsigned)bb*8192u + (unsigned)cellA;

    // step 0: h1(0) = f(x0), no MFMA
    if (l < 16){
      const float xt = xs[0];
      float g4[4];
      #pragma unroll
      for (int g = 0; g < 4; ++g) g4[g] = __builtin_fmaf(xt, wxA[g], biasA[g]);
      c1 = sigmoid_f(g4[1]) * c1 + sigmoid_f(g4[0]) * tanh_f(g4[2]);
      const float hv = sigmoid_f(g4[3]) * tanh_f(c1);
      H1R[0][cellA] = (_Float16)hv;
      __hip_atomic_store(&ring[ringBase],
                         __float_as_uint(hv),
                         __ATOMIC_RELAXED, __HIP_MEMORY_SCOPE_AGENT);
    }

    unsigned cachedCons = 0;
    #pragma unroll 1
    for (int s = 1; s < TB; ++s){
      const bool pub = ((s & 7) == 2) && (s >= 10);
      if (pub) asm volatile("s_waitcnt vmcnt(2)" ::: "memory");  // chunk retired

      // ---- back-pressure poll BEFORE the single barrier (trim 1).
      //      Read-only; all chunk-C ring stores sit after the barrier, and
      //      no wave passes it until wave0 clears this. ----
      if (((s & 7) == 0) && s >= 64 && w == 0 && l == 0){
        const unsigned need = (unsigned)((s >> 3) - 7);
        if (cachedCons < need){
          int gd = 0;
          while (cachedCons < need && gd++ < (1 << 20)){
            cachedCons = __hip_atomic_load(&consFlag[bb], __ATOMIC_ACQUIRE,
                                           __HIP_MEMORY_SCOPE_AGENT);
            if (cachedCons < need) __builtin_amdgcn_s_sleep(2);
          }
        }
      }
      RAWBAR();   // the ONLY barrier this step

      // a1 fragment loads immediately at barrier release (R20 trim)
      const f16x8* pA1 = (const f16x8*)&H1R[(s-1)&7][0];
      const f16x8 a10 = pA1[quad],     a11 = pA1[4+quad],
                  a12 = pA1[8+quad],   a13 = pA1[12+quad];

      if (pub && w == 0 && l == 0)
        __hip_atomic_store(&prodFlag[bb], (unsigned)(((s - 10) >> 3) + 1),
                           __ATOMIC_RELAXED, __HIP_MEMORY_SCOPE_AGENT);

      // ---- R18-verified MFMA shape: 8 independent heads, then 8 deps ----
      f32x4 aLo[4], aHi[4];
      #pragma unroll
      for (int g = 0; g < 4; ++g){
        aLo[g] = MFMA16(a10, B1[4*g+0], zacc);
        aHi[g] = MFMA16(a12, B1[4*g+2], zacc);
      }
      #pragma unroll
      for (int g = 0; g < 4; ++g){
        aLo[g] = MFMA16(a11, B1[4*g+1], aLo[g]);
        aHi[g] = MFMA16(a13, B1[4*g+3], aHi[g]);
      }
      if (l < 16){
        const float xt = xs[s];
        // ---- trim 2: c1 chain from gates 0..2 first (their MFMAs finish
        //      ~115cy before the issue wall); gate 3 read LAST so only
        //      sigma(g3)*tc + cvt + write are post-wall. Identical ops. ----
        const float g0 = aLo[0][0] + aHi[0][0] + __builtin_fmaf(xt, wxA[0], biasA[0]);
        const float g1 = aLo[1][0] + aHi[1][0] + __builtin_fmaf(xt, wxA[1], biasA[1]);
        const float g2 = aLo[2][0] + aHi[2][0] + __builtin_fmaf(xt, wxA[2], biasA[2]);
        c1 = sigmoid_f(g1) * c1 + sigmoid_f(g0) * tanh_f(g2);
        const float tc = tanh_f(c1);
        const float g3 = aLo[3][0] + aHi[3][0] + __builtin_fmaf(xt, wxA[3], biasA[3]);
        const float hv = sigmoid_f(g3) * tc;
        H1R[s&7][cellA] = (_Float16)hv;
        __hip_atomic_store(&ring[ringBase + (unsigned)((s & 63) << 7)],
                           __float_as_uint(hv),
                           __ATOMIC_RELAXED, __HIP_MEMORY_SCOPE_AGENT);
      }
    }
    // final: drain everything, publish chunk 127 (flag = 128)
    asm volatile("s_waitcnt vmcnt(0)" ::: "memory");
    RAWBAR();
    if (w == 0 && l == 0)
      __hip_atomic_store(&prodFlag[bb], 128u,
                         __ATOMIC_RELEASE, __HIP_MEMORY_SCOPE_AGENT);

  } else {
    // ===================== L2 CONSUMER (batch bb) — R18 verbatim ==========
    const int bb = blockIdx.x - 128;
    f16x8 B2i[16], B2h[8];
    float biasB[4] = {0,0,0,0};
    if (w < 4){
      #pragma unroll
      for (int g = 0; g < 4; ++g){
        const int nB = (4*g + w)*16 + col;
        biasB[g] = b_ih2[nB] + b_hh2[nB];
        #pragma unroll
        for (int k = 0; k < 4; ++k)
          B2i[4*g + k] = load_frag(w_ih2 + nB*HID1 + k*32 + quad*8);
        #pragma unroll
        for (int k = 0; k < 2; ++k)
          B2h[2*g + k] = load_frag(w_hh2 + nB*EMB2 + k*32 + quad*8);
      }
    }
    if (t < EMB2) H2R[7][t] = (_Float16)0.0f;   // h2(-1) = 0
    if (t == 0) readyUpTo = 0u;
    __syncthreads();

    unsigned staged = 0;   // stager (wave 4) private progress
    float c2 = 0.0f;

    #define STAGE_ATTEMPT() do {                                              \
        if (staged < 128u){                                                   \
          const unsigned pf_ = __hip_atomic_load(&prodFlag[bb],               \
                                  __ATOMIC_ACQUIRE, __HIP_MEMORY_SCOPE_AGENT);\
          asm volatile("" ::: "memory");                                      \
          __builtin_amdgcn_sched_barrier(0);                                  \
          if (pf_ > staged){                                                  \
            const float4* rp_ = (const float4*)(ring                          \
                + (unsigned)(bb*8 + (staged&7))*1024u + (unsigned)l*16u);     \
            const float4 v0_ = rp_[0], v1_ = rp_[1],                          \
                         v2_ = rp_[2], v3_ = rp_[3];                          \
            f16x8 p0_, p1_;                                                   \
            p0_[0]=(_Float16)v0_.x; p0_[1]=(_Float16)v0_.y;                   \
            p0_[2]=(_Float16)v0_.z; p0_[3]=(_Float16)v0_.w;                   \
            p0_[4]=(_Float16)v1_.x; p0_[5]=(_Float16)v1_.y;                   \
            p0_[6]=(_Float16)v1_.z; p0_[7]=(_Float16)v1_.w;                   \
            p1_[0]=(_Float16)v2_.x; p1_[1]=(_Float16)v2_.y;                   \
            p1_[2]=(_Float16)v2_.z; p1_[3]=(_Float16)v2_.w;                   \
            p1_[4]=(_Float16)v3_.x; p1_[5]=(_Float16)v3_.y;                   \
            p1_[6]=(_Float16)v3_.z; p1_[7]=(_Float16)v3_.w;                   \
            f16x8* dst_ = (f16x8*)&SH1[staged&1][0][0];                       \
            dst_[2*l] = p0_; dst_[2*l+1] = p1_;                               \
            asm volatile("" ::: "memory");                                    \
            if (l == 0){                                                      \
              __hip_atomic_store(&consFlag[bb], staged + 1u,                  \
                  __ATOMIC_RELAXED, __HIP_MEMORY_SCOPE_AGENT);                \
              readyUpTo = staged + 1u;                                        \
            }                                                                 \
            staged++;                                                         \
          }                                                                   \
        }                                                                     \
      } while(0)

    #pragma unroll 1
    for (int m = 0; m < TB; ++m){
      const int c = m >> 3;
      if ((m & 7) == 0){
        int gd = 0;
        while (*(volatile unsigned*)&readyUpTo < (unsigned)(c + 1)
               && gd++ < (1 << 20)){
          if (w == 4) STAGE_ATTEMPT();
          __syncthreads();
        }
        if (w == 4) STAGE_ATTEMPT();   // opportunistic prefetch of chunk c+1
      }

      if (w < 4){
        const f16x8* pA2 = (const f16x8*)&H2R[(m+7)&7][0];     // h2(m-1)
        const f16x8 a20 = pA2[quad], a21 = pA2[4+quad];
        const f16x8* pA1 = (const f16x8*)&SH1[c&1][m&7][0];    // staged h1(m)
        const f16x8 a10 = pA1[quad],    a11 = pA1[4+quad],
                    a12 = pA1[8+quad],  a13 = pA1[12+quad];
        f32x4 lo[4], hi[4];
        #pragma unroll
        for (int g = 0; g < 4; ++g){
          lo[g] = MFMA16(a10, B2i[4*g+0], zacc);
          hi[g] = MFMA16(a12, B2i[4*g+2], zacc);
        }
        #pragma unroll
        for (int g = 0; g < 4; ++g){
          lo[g] = MFMA16(a11, B2i[4*g+1], lo[g]);
          hi[g] = MFMA16(a13, B2i[4*g+3], hi[g]);
        }
        #pragma unroll
        for (int g = 0; g < 4; ++g){
          lo[g] = MFMA16(a20, B2h[2*g+0], lo[g]);
          hi[g] = MFMA16(a21, B2h[2*g+1], hi[g]);
        }
        if (l < 16){
          float g4[4];
          #pragma unroll
          for (int g = 0; g < 4; ++g) g4[g] = lo[g][0] + hi[g][0] + biasB[g];
          c2 = sigmoid_f(g4[1]) * c2 + sigmoid_f(g4[0]) * tanh_f(g4[2]);
          const float hv = sigmoid_f(g4[3]) * tanh_f(c2);
          if (m < TB-1) H2R[m&7][16*w + l] = (_Float16)hv;
          else          out[bb * EMB2 + 16*w + l] = hv;
        }
      }
      __syncthreads();
    }
    #undef STAGE_ATTEMPT
  }
}

extern "C" void kernel_launch(void* const* d_in, const int* in_sizes, int n_in,
                              void* d_out, int out_size, void* d_ws, size_t ws_size,
                              hipStream_t stream) {
  // zero the 256 flag counters each launch (stream-ordered, graph-capturable)
  hipMemsetAsync(d_ws, 0, 256 * sizeof(unsigned), stream);
  lstm2_kernel<<<dim3(256), dim3(512), 0, stream>>>(
      (const float*)d_in[0],   // x
      (const float*)d_in[1],   // w_ih1
      (const float*)d_in[2],   // w_hh1
      (const float*)d_in[3],   // b_ih1
      (const float*)d_in[4],   // b_hh1
      (const float*)d_in[5],   // w_ih2
      (const float*)d_in[6],   // w_hh2
      (const float*)d_in[7],   // b_ih2
      (const float*)d_in[8],   // b_hh2
      (float*)d_out,
      (unsigned*)d_ws);
}